// Round 4
// baseline (81.991 us; speedup 1.0000x reference)
//
#include <hip/hip_runtime.h>
#include <math.h>

#define NB 64
#define NP 8732
#define NM 16
#define NC 21
#define BG 20
#define NPB ((NP + 255) / 256)   // 35 blocks of 256 per image
#define VPL 137                  // values per lane in hardneg (64*137 >= 8732)

// -------- workspace layout (bytes) --------
// [0,     4096)  obj_idx  int[NB*NM]
// [4096,  4352)  n_pos    int[NB]      (zeroed by kernel A each launch)
// [4352,  4608)  hn_sum   float[NB]
// [4608,  4612)  done     int          (zeroed by kernel A each launch)
// [4864, 13824)  loc_part float[NB*NPB]
// [13824,22784)  cep_part float[NB*NPB]
// [24576, ... )  ce_neg   float[NB*NP]

// Kernel A: per (b,m) argmax_p IoU(box, prior) -- first-occurrence ties.
// Also zeroes n_pos/done (replaces the 40us in-graph memset node, round-3 lesson).
__global__ void obj_argmax_kernel(const float* __restrict__ b_boxes,
                                  const float* __restrict__ priors,
                                  int* __restrict__ obj_idx,
                                  int* __restrict__ n_pos,
                                  int* __restrict__ done) {
    int bm = blockIdx.x;
    int tid = threadIdx.x;
    if (tid == 0) {
        if ((bm & (NM - 1)) == 0) n_pos[bm / NM] = 0;
        if (bm == 0) *done = 0;
    }
    const float* box = b_boxes + (size_t)bm * 4;
    float ax1 = box[0], ay1 = box[1], ax2 = box[2], ay2 = box[3];
    float area_a = (ax2 - ax1) * (ay2 - ay1);
    float best = -1.0f;
    int bi = 0x7fffffff;
    for (int p = tid; p < NP; p += 256) {
        float4 pr = ((const float4*)priors)[p];
        float bx1 = pr.x - pr.z * 0.5f;
        float by1 = pr.y - pr.w * 0.5f;
        float bx2 = pr.x + pr.z * 0.5f;
        float by2 = pr.y + pr.w * 0.5f;
        float w = fminf(ax2, bx2) - fmaxf(ax1, bx1); w = fmaxf(w, 0.0f);
        float h = fminf(ay2, by2) - fmaxf(ay1, by1); h = fmaxf(h, 0.0f);
        float inter = w * h;
        float area_b = (bx2 - bx1) * (by2 - by1);
        float iou = inter / (area_a + area_b - inter);
        if (iou > best) { best = iou; bi = p; }   // strict > keeps lowest p in-thread
    }
    __shared__ float sv[256];
    __shared__ int   si[256];
    sv[tid] = best; si[tid] = bi;
    __syncthreads();
    for (int s = 128; s > 0; s >>= 1) {
        if (tid < s) {
            if (sv[tid + s] > sv[tid] ||
                (sv[tid + s] == sv[tid] && si[tid + s] < si[tid])) {
                sv[tid] = sv[tid + s];
                si[tid] = si[tid + s];
            }
        }
        __syncthreads();
    }
    if (tid == 0) obj_idx[bm] = si[0];
}

// Kernel B: per prior -> match, pos, tc, true_locs, CE; block partials.
// pred_cls staged through LDS: float4 coalesced stage (5.25 loads/thread)
// instead of 21 scalar VMEM issues/thread. (b*NP+p0)*NC is 16B-aligned
// because NP%4==0 and p0%4==0. Stride-21 LDS reads: 2-way max = free.
__global__ void match_ce_kernel(const float* __restrict__ pred_loc,
                                const float* __restrict__ pred_cls,
                                const float* __restrict__ b_boxes,
                                const int*   __restrict__ b_labels,
                                const float* __restrict__ priors,
                                const int*   __restrict__ obj_idx,
                                float* __restrict__ ce_neg,
                                int*   __restrict__ n_pos,
                                float* __restrict__ loc_part,
                                float* __restrict__ cep_part) {
    int blk = blockIdx.x;
    int b = blk / NPB;
    int chunk = blk % NPB;
    int tid = threadIdx.x;
    int p0 = chunk * 256;
    int p = p0 + tid;

    __shared__ float scls[256 * NC];           // 21504 B
    __shared__ float4 sbox[NM];
    __shared__ int sobj[NM], slab[NM];

    int pcount = NP - p0; if (pcount > 256) pcount = 256;
    int n4 = (pcount * NC) >> 2;               // exact: pcount%4==0 in all chunks
    const float4* src4 = (const float4*)(pred_cls + (size_t)(b * NP + p0) * NC);
    for (int k = tid; k < n4; k += 256) ((float4*)scls)[k] = src4[k];

    if (tid < NM) {
        sbox[tid] = ((const float4*)b_boxes)[b * NM + tid];
        sobj[tid] = obj_idx[b * NM + tid];
        slab[tid] = b_labels[b * NM + tid];
    }
    __syncthreads();

    float locpart = 0.0f, ceppart = 0.0f;
    int npart = 0;

    if (p < NP) {
        float4 pr = ((const float4*)priors)[p];
        float px1 = pr.x - pr.z * 0.5f, py1 = pr.y - pr.w * 0.5f;
        float px2 = pr.x + pr.z * 0.5f, py2 = pr.y + pr.w * 0.5f;
        float area_b = (px2 - px1) * (py2 - py1);

        float best = -1.0f;
        int bm = 0;
        bool pos = false;
#pragma unroll
        for (int m = 0; m < NM; ++m) {
            float4 bx = sbox[m];
            float w = fminf(bx.z, px2) - fmaxf(bx.x, px1); w = fmaxf(w, 0.0f);
            float h = fminf(bx.w, py2) - fmaxf(bx.y, py1); h = fmaxf(h, 0.0f);
            float inter = w * h;
            float area_a = (bx.z - bx.x) * (bx.w - bx.y);
            float iou = inter / (area_a + area_b - inter);
            if (p == sobj[m]) iou = 1.0f;          // force-match
            pos = pos || (iou >= 0.5f);
            if (iou > best) { best = iou; bm = m; } // first-occurrence argmax over m
        }
        int lab = slab[bm];
        // replicate reference: tc = label*sign; where(tc<0, BG, tc).
        // -0.0 < 0 is False -> negative prior with label 0 stays class 0.
        int tc = pos ? lab : ((lab == 0) ? 0 : BG);

        float4 bx = sbox[bm];
        float bcx = (bx.x + bx.z) * 0.5f, bcy = (bx.y + bx.w) * 0.5f;
        float bw = bx.z - bx.x, bh = bx.w - bx.y;
        float g0 = (bcx - pr.x) / (pr.z / 10.0f);
        float g1 = (bcy - pr.y) / (pr.w / 10.0f);
        float g2 = logf(bw / pr.z) * 5.0f;
        float g3 = logf(bh / pr.w) * 5.0f;

        float4 plv = ((const float4*)pred_loc)[(size_t)b * NP + p];
        if (pos) {
            locpart = fabsf(plv.x - g0) + fabsf(plv.y - g1) +
                      fabsf(plv.z - g2) + fabsf(plv.w - g3);
            npart = 1;
        }

        const float* lg = scls + tid * NC;
        float l[NC];
        float mx = -INFINITY, ltc = 0.0f;
#pragma unroll
        for (int c = 0; c < NC; ++c) {
            l[c] = lg[c];
            mx = fmaxf(mx, l[c]);
            ltc = (c == tc) ? l[c] : ltc;
        }
        float se = 0.0f;
#pragma unroll
        for (int c = 0; c < NC; ++c) se += expf(l[c] - mx);
        float ce = mx + logf(se) - ltc;

        ce_neg[(size_t)b * NP + p] = pos ? 0.0f : ce;
        if (pos) ceppart = ce;
    }

    // block reductions (deterministic)
    __shared__ float rf[256];
    __shared__ int ri[256];
    rf[tid] = locpart; ri[tid] = npart;
    __syncthreads();
    for (int s = 128; s > 0; s >>= 1) {
        if (tid < s) { rf[tid] += rf[tid + s]; ri[tid] += ri[tid + s]; }
        __syncthreads();
    }
    if (tid == 0) {
        loc_part[blk] = rf[0];
        atomicAdd(&n_pos[b], ri[0]);   // int atomic: order-independent
    }
    __syncthreads();
    rf[tid] = ceppart;
    __syncthreads();
    for (int s = 128; s > 0; s >>= 1) {
        if (tid < s) rf[tid] += rf[tid + s];
        __syncthreads();
    }
    if (tid == 0) cep_part[blk] = rf[0];
}

// Kernel C: per-image top-K sum (one wave per image, register-resident radix
// select, pure-VALU counting, one shfl reduce per pass) + fused finalize:
// the last block to finish (device-scope ticket) reduces all partials.
__global__ void __launch_bounds__(64) hardneg_kernel(const float* __restrict__ ce_neg,
                                                     const int* __restrict__ n_pos,
                                                     float* __restrict__ hn_sum,
                                                     const float* __restrict__ loc_part,
                                                     const float* __restrict__ cep_part,
                                                     int* __restrict__ done,
                                                     float* __restrict__ out) {
    int b = blockIdx.x;
    int lane = threadIdx.x;

    int K = 3 * n_pos[b];
    if (K > NP) K = NP;

    float result = 0.0f;
    if (K > 0) {
        const float* src = ce_neg + (size_t)b * NP;
        unsigned v[VPL];
#pragma unroll
        for (int j = 0; j < VPL; ++j) {
            int i = lane + j * 64;                          // coalesced
            v[j] = (i < NP) ? __float_as_uint(src[i]) : 0u; // pad 0: never counted
        }

        unsigned V = 0;
        bool exact = false;
#pragma unroll 1
        for (int bit = 30; bit >= 9; --bit) {
            unsigned cand = V | (1u << bit);
            int c = 0;
#pragma unroll
            for (int j = 0; j < VPL; ++j) c += (v[j] >= cand) ? 1 : 0;  // pure VALU
#pragma unroll
            for (int o = 32; o > 0; o >>= 1) c += __shfl_xor(c, o);
            if (c >= K) {
                V = cand;
                if (c == K) { exact = true; break; }   // {u >= V} is exactly top-K
            }
        }

        float sum = 0.0f;
        if (exact) {
#pragma unroll
            for (int j = 0; j < VPL; ++j)
                if (v[j] >= V) sum += __uint_as_float(v[j]);
#pragma unroll
            for (int o = 32; o > 0; o >>= 1) sum += __shfl_xor(sum, o);
            result = sum;
        } else {
            int cgt = 0;
#pragma unroll
            for (int j = 0; j < VPL; ++j) {
                bool g = v[j] > V;
                cgt += g ? 1 : 0;
                sum += g ? __uint_as_float(v[j]) : 0.0f;
            }
#pragma unroll
            for (int o = 32; o > 0; o >>= 1) {
                sum += __shfl_xor(sum, o);
                cgt += __shfl_xor(cgt, o);
            }
            result = sum + (float)(K - cgt) * __uint_as_float(V);
        }
    }

    if (lane == 0) hn_sum[b] = result;

    // last-block ticket: release (fence) -> atomic -> acquire (fence) -> reduce
    __threadfence();
    __shared__ int amlast;
    if (lane == 0) amlast = (atomicAdd(done, 1) == NB - 1) ? 1 : 0;
    __syncthreads();
    if (amlast) {
        __threadfence();
        float lsum = 0.0f, csum = 0.0f;
        for (int i = lane; i < NB * NPB; i += 64) {
            lsum += loc_part[i];
            csum += cep_part[i];
        }
        float hsum = hn_sum[lane];
        int np = n_pos[lane];
#pragma unroll
        for (int o = 32; o > 0; o >>= 1) {
            lsum += __shfl_xor(lsum, o);
            csum += __shfl_xor(csum, o);
            hsum += __shfl_xor(hsum, o);
            np   += __shfl_xor(np, o);
        }
        if (lane == 0) {
            float npt = (float)np;
            float loc_loss = lsum / (npt * 4.0f);     // ALPHA = 1.0
            float conf_loss = (hsum + csum) / npt;
            out[0] = conf_loss + loc_loss;
            out[1] = loc_loss;
            out[2] = conf_loss;
        }
    }
}

extern "C" void kernel_launch(void* const* d_in, const int* in_sizes, int n_in,
                              void* d_out, int out_size, void* d_ws, size_t ws_size,
                              hipStream_t stream) {
    const float* pred_loc  = (const float*)d_in[0];
    const float* pred_cls  = (const float*)d_in[1];
    const float* b_boxes   = (const float*)d_in[2];
    const int*   b_labels  = (const int*)d_in[3];
    const float* priors    = (const float*)d_in[4];

    char* ws = (char*)d_ws;
    int*   obj_idx  = (int*)(ws);
    int*   n_pos    = (int*)(ws + 4096);
    float* hn_sum   = (float*)(ws + 4352);
    int*   done     = (int*)(ws + 4608);
    float* loc_part = (float*)(ws + 4864);
    float* cep_part = (float*)(ws + 13824);
    float* ce_neg   = (float*)(ws + 24576);
    float* out = (float*)d_out;

    obj_argmax_kernel<<<NB * NM, 256, 0, stream>>>(b_boxes, priors, obj_idx, n_pos, done);
    match_ce_kernel<<<NB * NPB, 256, 0, stream>>>(pred_loc, pred_cls, b_boxes,
                                                  b_labels, priors, obj_idx,
                                                  ce_neg, n_pos, loc_part, cep_part);
    hardneg_kernel<<<NB, 64, 0, stream>>>(ce_neg, n_pos, hn_sum,
                                          loc_part, cep_part, done, out);
}

// Round 5
// 78.696 us; speedup vs baseline: 1.0419x; 1.0419x over previous
//
#include <hip/hip_runtime.h>
#include <math.h>

#define NB 64
#define NP 8732
#define NM 16
#define NC 21
#define BG 20
#define NCH 35                   // 256-prior chunks per image
#define VPL 137                  // values per lane in topK (64*137 >= 8732)

// -------- workspace layout (bytes) --------
// [0,      8960)  np_part  int[NB*NCH]
// [9216,  18176)  loc_part f32[NB*NCH]
// [18432, 27392)  cep_part f32[NB*NCH]
// [28672, 315392) argm     u64[NB*NCH*16]   per-block per-object packed argmax
// [315392,315396) done     int              (zeroed by K1 blk0)
// [315648,315904) np_img   int[NB]
// [315904,316160) loc_img  f32[NB]
// [316160,316416) cep_img  f32[NB]
// [316416,316672) hn_img   f32[NB]
// [320512, ...)   ce_neg   f32[NB*NP]

// Kernel 1: one full-chip pass over all (b,p).
// Computes the 16 IoUs ONCE per prior, serving both directions:
//  - per-prior best object (raw, no force-match) -> pos/tc/loc/CE
//  - per-object argmax over priors -> packed u64 block partials (no atomics)
__global__ void __launch_bounds__(256) match_kernel(
    const float* __restrict__ pred_loc, const float* __restrict__ pred_cls,
    const float* __restrict__ b_boxes, const int* __restrict__ b_labels,
    const float* __restrict__ priors,
    float* __restrict__ ce_neg, int* __restrict__ np_part,
    float* __restrict__ loc_part, float* __restrict__ cep_part,
    unsigned long long* __restrict__ argm, int* __restrict__ done)
{
    int blk = blockIdx.x;
    int b = blk / NCH, chunk = blk % NCH;
    int tid = threadIdx.x;
    int lane = tid & 63, wid = tid >> 6;
    int p = chunk * 256 + tid;
    if (blk == 0 && tid == 0) *done = 0;   // consumed only by K2 (stream-ordered)

    __shared__ float4 sbox[NM];
    __shared__ int slab[NM];
    __shared__ unsigned long long swm[4][NM];
    if (tid < NM) {
        sbox[tid] = ((const float4*)b_boxes)[b * NM + tid];
        slab[tid] = b_labels[b * NM + tid];
    }
    __syncthreads();

    bool act = p < NP;
    float4 pr = act ? ((const float4*)priors)[p] : make_float4(0.f, 0.f, 1.f, 1.f);
    float px1 = pr.x - pr.z * 0.5f, py1 = pr.y - pr.w * 0.5f;
    float px2 = pr.x + pr.z * 0.5f, py2 = pr.y + pr.w * 0.5f;
    float area_b = (px2 - px1) * (py2 - py1);

    unsigned long long bm[NM];
    float best = -1.0f;
    int bmi = 0;
#pragma unroll
    for (int m = 0; m < NM; ++m) {
        float4 bx = sbox[m];
        float w = fminf(bx.z, px2) - fmaxf(bx.x, px1); w = fmaxf(w, 0.0f);
        float h = fminf(bx.w, py2) - fmaxf(bx.y, py1); h = fmaxf(h, 0.0f);
        float inter = w * h;
        float area_a = (bx.z - bx.x) * (bx.w - bx.y);
        float iou = inter / (area_a + area_b - inter);
        // packed candidate for per-object argmax: ties -> lowest p wins (max ~p)
        bm[m] = act ? ((unsigned long long)__float_as_uint(iou) << 32)
                      | (unsigned)(~p)
                    : 0ull;
        if (act && iou > best) { best = iou; bmi = m; }  // first-occurrence over m
    }

    // per-object argmax reduction: wave shfl -> cross-wave LDS -> block partial
#pragma unroll
    for (int m = 0; m < NM; ++m) {
        unsigned long long x = bm[m];
#pragma unroll
        for (int o = 32; o > 0; o >>= 1) {
            unsigned long long y = __shfl_xor(x, o);
            x = (y > x) ? y : x;
        }
        bm[m] = x;
    }
    if (lane == 0) {
#pragma unroll
        for (int m = 0; m < NM; ++m) swm[wid][m] = bm[m];
    }
    __syncthreads();
    if (tid < NM) {
        unsigned long long x = swm[0][tid];
#pragma unroll
        for (int w = 1; w < 4; ++w) x = (swm[w][tid] > x) ? swm[w][tid] : x;
        argm[(size_t)blk * NM + tid] = x;
    }

    float locpart = 0.0f, ceppart = 0.0f;
    int npart = 0;
    if (act) {
        bool pos = best >= 0.5f;                    // raw (no force-match)
        int lab = slab[bmi];
        // ref quirk: tc = label*sign; where(tc<0,BG,tc); -0.0<0 False -> label 0 stays 0
        int tc = pos ? lab : ((lab == 0) ? 0 : BG);

        float4 bx = sbox[bmi];
        float bcx = (bx.x + bx.z) * 0.5f, bcy = (bx.y + bx.w) * 0.5f;
        float bw = bx.z - bx.x, bh = bx.w - bx.y;
        float g0 = (bcx - pr.x) / (pr.z / 10.0f);
        float g1 = (bcy - pr.y) / (pr.w / 10.0f);
        float g2 = logf(bw / pr.z) * 5.0f;
        float g3 = logf(bh / pr.w) * 5.0f;

        float4 plv = ((const float4*)pred_loc)[(size_t)b * NP + p];
        if (pos) {
            locpart = fabsf(plv.x - g0) + fabsf(plv.y - g1) +
                      fabsf(plv.z - g2) + fabsf(plv.w - g3);
            npart = 1;
        }

        const float* lg = pred_cls + (size_t)(b * NP + p) * NC;
        float l[NC];
        float mx = -INFINITY, ltc = 0.0f;
#pragma unroll
        for (int c = 0; c < NC; ++c) {
            l[c] = lg[c];
            mx = fmaxf(mx, l[c]);
            ltc = (c == tc) ? l[c] : ltc;
        }
        float se = 0.0f;
#pragma unroll
        for (int c = 0; c < NC; ++c) se += expf(l[c] - mx);
        float ce = mx + logf(se) - ltc;

        ce_neg[(size_t)b * NP + p] = pos ? 0.0f : ce;
        if (pos) ceppart = ce;
    }

    __shared__ float rf[256];
    __shared__ int ri[256];
    rf[tid] = locpart; ri[tid] = npart;
    __syncthreads();
    for (int s = 128; s > 0; s >>= 1) {
        if (tid < s) { rf[tid] += rf[tid + s]; ri[tid] += ri[tid + s]; }
        __syncthreads();
    }
    if (tid == 0) { loc_part[blk] = rf[0]; np_part[blk] = ri[0]; }
    __syncthreads();
    rf[tid] = ceppart;
    __syncthreads();
    for (int s = 128; s > 0; s >>= 1) {
        if (tid < s) rf[tid] += rf[tid + s];
        __syncthreads();
    }
    if (tid == 0) cep_part[blk] = rf[0];
}

// Kernel 2: one wave per image.
//  (a) reduce per-object argmax partials -> obj_idx
//  (b) force-match FIX-UP: for each distinct forced prior, recompute its raw
//      contribution exactly and apply deltas; patch ce_neg[p*]=0 in global
//      (same-wave RAW ordered by s_waitcnt vmcnt(0); CDNA L1 is write-through)
//  (c) register radix top-K (round-3 proven: pure-VALU counts, shfl per pass)
//  (d) last-block ticket does the global finalize
__global__ void __launch_bounds__(64) select_kernel(
    const float* __restrict__ pred_loc, const float* __restrict__ pred_cls,
    const float* __restrict__ b_boxes, const int* __restrict__ b_labels,
    const float* __restrict__ priors,
    float* __restrict__ ce_neg,
    const int* __restrict__ np_part, const float* __restrict__ loc_part,
    const float* __restrict__ cep_part,
    const unsigned long long* __restrict__ argm,
    int* __restrict__ done,
    int* __restrict__ np_img, float* __restrict__ loc_img,
    float* __restrict__ cep_img, float* __restrict__ hn_img,
    float* __restrict__ out)
{
    int b = blockIdx.x;
    int lane = threadIdx.x;

    __shared__ float4 sbox[NM];
    __shared__ int slab[NM], sobj[NM];
    if (lane < NM) {
        sbox[lane] = ((const float4*)b_boxes)[b * NM + lane];
        slab[lane] = b_labels[b * NM + lane];
        unsigned long long x = 0;
        for (int c = 0; c < NCH; ++c) {
            unsigned long long y = argm[(size_t)(b * NCH + c) * NM + lane];
            x = (y > x) ? y : x;
        }
        sobj[lane] = (int)(~(unsigned)(x & 0xffffffffull));
    }
    __syncthreads();

    float dloc = 0.0f, dcep = 0.0f;
    int dnp = 0;
    if (lane < NM) {
        int pstar = sobj[lane];
        bool first = true;
        for (int m2 = 0; m2 < lane; ++m2) if (sobj[m2] == pstar) first = false;
        if (first) {
            float4 pr = ((const float4*)priors)[pstar];
            float px1 = pr.x - pr.z * 0.5f, py1 = pr.y - pr.w * 0.5f;
            float px2 = pr.x + pr.z * 0.5f, py2 = pr.y + pr.w * 0.5f;
            float area_b = (px2 - px1) * (py2 - py1);
            float best = -1.0f; int bmi = 0;
            float gg[NM][4];
#pragma unroll
            for (int m = 0; m < NM; ++m) {
                float4 bx = sbox[m];
                float w = fminf(bx.z, px2) - fmaxf(bx.x, px1); w = fmaxf(w, 0.0f);
                float h = fminf(bx.w, py2) - fmaxf(bx.y, py1); h = fmaxf(h, 0.0f);
                float inter = w * h;
                float area_a = (bx.z - bx.x) * (bx.w - bx.y);
                float iou = inter / (area_a + area_b - inter);
                if (iou > best) { best = iou; bmi = m; }   // same order as K1
                float bcx = (bx.x + bx.z) * 0.5f, bcy = (bx.y + bx.w) * 0.5f;
                gg[m][0] = (bcx - pr.x) / (pr.z / 10.0f);
                gg[m][1] = (bcy - pr.y) / (pr.w / 10.0f);
                gg[m][2] = logf((bx.z - bx.x) / pr.z) * 5.0f;
                gg[m][3] = logf((bx.w - bx.y) / pr.w) * 5.0f;
            }
            bool pos_raw = best >= 0.5f;
            int lab_raw = slab[bmi];
            int tc_raw = pos_raw ? lab_raw : ((lab_raw == 0) ? 0 : BG);
            int tc_new = slab[lane];                 // forced match to object `lane`

            const float* lg = pred_cls + (size_t)(b * NP + pstar) * NC;
            float l[NC];
            float mx = -INFINITY;
#pragma unroll
            for (int c = 0; c < NC; ++c) { l[c] = lg[c]; mx = fmaxf(mx, l[c]); }
            float se = 0.0f;
#pragma unroll
            for (int c = 0; c < NC; ++c) se += expf(l[c] - mx);
            float lraw_tc = 0.0f, lnew_tc = 0.0f;
#pragma unroll
            for (int c = 0; c < NC; ++c) {
                lraw_tc = (c == tc_raw) ? l[c] : lraw_tc;
                lnew_tc = (c == tc_new) ? l[c] : lnew_tc;
            }
            float lse = mx + logf(se);
            float ce_raw = lse - lraw_tc;
            float ce_new = lse - lnew_tc;

            float4 plv = ((const float4*)pred_loc)[(size_t)b * NP + pstar];
            float loc_raw = fabsf(plv.x - gg[bmi][0]) + fabsf(plv.y - gg[bmi][1]) +
                            fabsf(plv.z - gg[bmi][2]) + fabsf(plv.w - gg[bmi][3]);
            float loc_new = fabsf(plv.x - gg[lane][0]) + fabsf(plv.y - gg[lane][1]) +
                            fabsf(plv.z - gg[lane][2]) + fabsf(plv.w - gg[lane][3]);

            dnp  = pos_raw ? 0 : 1;
            dloc = loc_new - (pos_raw ? loc_raw : 0.0f);
            dcep = ce_new - (pos_raw ? ce_raw : 0.0f);
            ce_neg[(size_t)b * NP + pstar] = 0.0f;   // now positive -> excluded
        }
    }
    // order the patch stores before the top-K loads (same wave, write-through L1)
    asm volatile("s_waitcnt vmcnt(0)" ::: "memory");

    // per-image sums: 35 block partials + fix-up deltas
    int   np_s  = ((lane < NCH) ? np_part[b * NCH + lane]  : 0)    + dnp;
    float loc_s = ((lane < NCH) ? loc_part[b * NCH + lane] : 0.0f) + dloc;
    float cep_s = ((lane < NCH) ? cep_part[b * NCH + lane] : 0.0f) + dcep;
#pragma unroll
    for (int o = 32; o > 0; o >>= 1) {
        np_s  += __shfl_xor(np_s, o);
        loc_s += __shfl_xor(loc_s, o);
        cep_s += __shfl_xor(cep_s, o);
    }

    int K = 3 * np_s;
    if (K > NP) K = NP;

    float result = 0.0f;
    if (K > 0) {
        const float* src = ce_neg + (size_t)b * NP;
        unsigned v[VPL];
#pragma unroll
        for (int j = 0; j < VPL; ++j) {
            int i = lane + j * 64;
            v[j] = (i < NP) ? __float_as_uint(src[i]) : 0u;
        }
        unsigned V = 0;
        bool exact = false;
#pragma unroll 1
        for (int bit = 30; bit >= 9; --bit) {
            unsigned cand = V | (1u << bit);
            int c = 0;
#pragma unroll
            for (int j = 0; j < VPL; ++j) c += (v[j] >= cand) ? 1 : 0;
#pragma unroll
            for (int o = 32; o > 0; o >>= 1) c += __shfl_xor(c, o);
            if (c >= K) {
                V = cand;
                if (c == K) { exact = true; break; }
            }
        }
        float sum = 0.0f;
        if (exact) {
#pragma unroll
            for (int j = 0; j < VPL; ++j)
                if (v[j] >= V) sum += __uint_as_float(v[j]);
#pragma unroll
            for (int o = 32; o > 0; o >>= 1) sum += __shfl_xor(sum, o);
            result = sum;
        } else {
            int cgt = 0;
#pragma unroll
            for (int j = 0; j < VPL; ++j) {
                bool g = v[j] > V;
                cgt += g ? 1 : 0;
                sum += g ? __uint_as_float(v[j]) : 0.0f;
            }
#pragma unroll
            for (int o = 32; o > 0; o >>= 1) {
                sum += __shfl_xor(sum, o);
                cgt += __shfl_xor(cgt, o);
            }
            result = sum + (float)(K - cgt) * __uint_as_float(V);
        }
    }

    if (lane == 0) {
        np_img[b] = np_s; loc_img[b] = loc_s; cep_img[b] = cep_s; hn_img[b] = result;
    }

    __threadfence();
    int amlast = 0;
    if (lane == 0) amlast = (atomicAdd(done, 1) == NB - 1) ? 1 : 0;
    amlast = __shfl(amlast, 0);
    if (amlast) {
        __threadfence();
        float l2 = loc_img[lane], c2 = cep_img[lane], h2 = hn_img[lane];
        int n2 = np_img[lane];
#pragma unroll
        for (int o = 32; o > 0; o >>= 1) {
            l2 += __shfl_xor(l2, o);
            c2 += __shfl_xor(c2, o);
            h2 += __shfl_xor(h2, o);
            n2 += __shfl_xor(n2, o);
        }
        if (lane == 0) {
            float npt = (float)n2;
            float loc_loss = l2 / (npt * 4.0f);     // ALPHA = 1.0
            float conf_loss = (h2 + c2) / npt;
            out[0] = conf_loss + loc_loss;
            out[1] = loc_loss;
            out[2] = conf_loss;
        }
    }
}

extern "C" void kernel_launch(void* const* d_in, const int* in_sizes, int n_in,
                              void* d_out, int out_size, void* d_ws, size_t ws_size,
                              hipStream_t stream) {
    const float* pred_loc  = (const float*)d_in[0];
    const float* pred_cls  = (const float*)d_in[1];
    const float* b_boxes   = (const float*)d_in[2];
    const int*   b_labels  = (const int*)d_in[3];
    const float* priors    = (const float*)d_in[4];

    char* ws = (char*)d_ws;
    int*   np_part  = (int*)(ws);
    float* loc_part = (float*)(ws + 9216);
    float* cep_part = (float*)(ws + 18432);
    unsigned long long* argm = (unsigned long long*)(ws + 28672);
    int*   done     = (int*)(ws + 315392);
    int*   np_img   = (int*)(ws + 315648);
    float* loc_img  = (float*)(ws + 315904);
    float* cep_img  = (float*)(ws + 316160);
    float* hn_img   = (float*)(ws + 316416);
    float* ce_neg   = (float*)(ws + 320512);
    float* out = (float*)d_out;

    match_kernel<<<NB * NCH, 256, 0, stream>>>(pred_loc, pred_cls, b_boxes,
                                               b_labels, priors, ce_neg, np_part,
                                               loc_part, cep_part, argm, done);
    select_kernel<<<NB, 64, 0, stream>>>(pred_loc, pred_cls, b_boxes, b_labels,
                                         priors, ce_neg, np_part, loc_part,
                                         cep_part, argm, done, np_img, loc_img,
                                         cep_img, hn_img, out);
}

// Round 6
// 63.640 us; speedup vs baseline: 1.2883x; 1.2366x over previous
//
#include <hip/hip_runtime.h>
#include <math.h>

#define NB 64
#define NP 8732
#define NM 16
#define NC 21
#define BG 20
#define NCH 35                   // 256-prior chunks per image
#define VPL 35                   // values per lane in topK (256*35 >= 8732)

// -------- workspace layout (bytes) --------
// [0,      8960)  np_part  int[NB*NCH]
// [9216,  18176)  loc_part f32[NB*NCH]
// [18432, 27392)  cep_part f32[NB*NCH]
// [28672, 315392) argm     u64[NB*NCH*16]   per-block per-object packed argmax
// [315392,315396) done     int              (zeroed by K1 blk0)
// [315648,315904) np_img   int[NB]
// [315904,316160) loc_img  f32[NB]
// [316160,316416) cep_img  f32[NB]
// [316416,316672) hn_img   f32[NB]
// [320512, ...)   ce_neg   f32[NB*NP]

// Kernel 1: one full-chip pass over all (b,p).
// Computes the 16 IoUs ONCE per prior, serving both directions:
//  - per-prior best object (raw, no force-match) -> pos/tc/loc/CE
//  - per-object argmax over priors -> packed u64 block partials (no atomics)
__global__ void __launch_bounds__(256) match_kernel(
    const float* __restrict__ pred_loc, const float* __restrict__ pred_cls,
    const float* __restrict__ b_boxes, const int* __restrict__ b_labels,
    const float* __restrict__ priors,
    float* __restrict__ ce_neg, int* __restrict__ np_part,
    float* __restrict__ loc_part, float* __restrict__ cep_part,
    unsigned long long* __restrict__ argm, int* __restrict__ done)
{
    int blk = blockIdx.x;
    int b = blk / NCH, chunk = blk % NCH;
    int tid = threadIdx.x;
    int lane = tid & 63, wid = tid >> 6;
    int p = chunk * 256 + tid;
    if (blk == 0 && tid == 0) *done = 0;   // consumed only by K2 (stream-ordered)

    __shared__ float4 sbox[NM];
    __shared__ int slab[NM];
    __shared__ unsigned long long swm[4][NM];
    if (tid < NM) {
        sbox[tid] = ((const float4*)b_boxes)[b * NM + tid];
        slab[tid] = b_labels[b * NM + tid];
    }
    __syncthreads();

    bool act = p < NP;
    float4 pr = act ? ((const float4*)priors)[p] : make_float4(0.f, 0.f, 1.f, 1.f);
    float px1 = pr.x - pr.z * 0.5f, py1 = pr.y - pr.w * 0.5f;
    float px2 = pr.x + pr.z * 0.5f, py2 = pr.y + pr.w * 0.5f;
    float area_b = (px2 - px1) * (py2 - py1);

    unsigned long long bm[NM];
    float best = -1.0f;
    int bmi = 0;
#pragma unroll
    for (int m = 0; m < NM; ++m) {
        float4 bx = sbox[m];
        float w = fminf(bx.z, px2) - fmaxf(bx.x, px1); w = fmaxf(w, 0.0f);
        float h = fminf(bx.w, py2) - fmaxf(bx.y, py1); h = fmaxf(h, 0.0f);
        float inter = w * h;
        float area_a = (bx.z - bx.x) * (bx.w - bx.y);
        float iou = inter / (area_a + area_b - inter);
        // packed candidate for per-object argmax: ties -> lowest p wins (max ~p)
        bm[m] = act ? ((unsigned long long)__float_as_uint(iou) << 32)
                      | (unsigned)(~p)
                    : 0ull;
        if (act && iou > best) { best = iou; bmi = m; }  // first-occurrence over m
    }

    // per-object argmax reduction: wave shfl -> cross-wave LDS -> block partial
#pragma unroll
    for (int m = 0; m < NM; ++m) {
        unsigned long long x = bm[m];
#pragma unroll
        for (int o = 32; o > 0; o >>= 1) {
            unsigned long long y = __shfl_xor(x, o);
            x = (y > x) ? y : x;
        }
        bm[m] = x;
    }
    if (lane == 0) {
#pragma unroll
        for (int m = 0; m < NM; ++m) swm[wid][m] = bm[m];
    }
    __syncthreads();
    if (tid < NM) {
        unsigned long long x = swm[0][tid];
#pragma unroll
        for (int w = 1; w < 4; ++w) x = (swm[w][tid] > x) ? swm[w][tid] : x;
        argm[(size_t)blk * NM + tid] = x;
    }

    float locpart = 0.0f, ceppart = 0.0f;
    int npart = 0;
    if (act) {
        bool pos = best >= 0.5f;                    // raw (no force-match)
        int lab = slab[bmi];
        // ref quirk: tc = label*sign; where(tc<0,BG,tc); -0.0<0 False -> label 0 stays 0
        int tc = pos ? lab : ((lab == 0) ? 0 : BG);

        float4 bx = sbox[bmi];
        float bcx = (bx.x + bx.z) * 0.5f, bcy = (bx.y + bx.w) * 0.5f;
        float bw = bx.z - bx.x, bh = bx.w - bx.y;
        float g0 = (bcx - pr.x) / (pr.z / 10.0f);
        float g1 = (bcy - pr.y) / (pr.w / 10.0f);
        float g2 = logf(bw / pr.z) * 5.0f;
        float g3 = logf(bh / pr.w) * 5.0f;

        float4 plv = ((const float4*)pred_loc)[(size_t)b * NP + p];
        if (pos) {
            locpart = fabsf(plv.x - g0) + fabsf(plv.y - g1) +
                      fabsf(plv.z - g2) + fabsf(plv.w - g3);
            npart = 1;
        }

        const float* lg = pred_cls + (size_t)(b * NP + p) * NC;
        float l[NC];
        float mx = -INFINITY, ltc = 0.0f;
#pragma unroll
        for (int c = 0; c < NC; ++c) {
            l[c] = lg[c];
            mx = fmaxf(mx, l[c]);
            ltc = (c == tc) ? l[c] : ltc;
        }
        float se = 0.0f;
#pragma unroll
        for (int c = 0; c < NC; ++c) se += expf(l[c] - mx);
        float ce = mx + logf(se) - ltc;

        ce_neg[(size_t)b * NP + p] = pos ? 0.0f : ce;
        if (pos) ceppart = ce;
    }

    __shared__ float rf[256];
    __shared__ int ri[256];
    rf[tid] = locpart; ri[tid] = npart;
    __syncthreads();
    for (int s = 128; s > 0; s >>= 1) {
        if (tid < s) { rf[tid] += rf[tid + s]; ri[tid] += ri[tid + s]; }
        __syncthreads();
    }
    if (tid == 0) { loc_part[blk] = rf[0]; np_part[blk] = ri[0]; }
    __syncthreads();
    rf[tid] = ceppart;
    __syncthreads();
    for (int s = 128; s > 0; s >>= 1) {
        if (tid < s) rf[tid] += rf[tid + s];
        __syncthreads();
    }
    if (tid == 0) cep_part[blk] = rf[0];
}

// Kernel 2: 256 threads (4 waves) per image.
//  (a) reduce per-object argmax partials -> obj_idx (parallel over 256 threads)
//  (b) force-match FIX-UP by tid<16: recompute raw contribution, apply deltas,
//      patch ce_neg[p*]=0 (no runtime-indexed local arrays -> no scratch)
//  (c) register radix top-K: v[35] per lane (FITS in VGPRs -- round-5 lesson:
//      v[137] at VGPR=80 was re-fetched from memory every pass, 43us stall),
//      pure-VALU counts, wave shfl + 4-entry LDS combine per pass
//  (d) last-block ticket does the global finalize
__global__ void __launch_bounds__(256) select_kernel(
    const float* __restrict__ pred_loc, const float* __restrict__ pred_cls,
    const float* __restrict__ b_boxes, const int* __restrict__ b_labels,
    const float* __restrict__ priors,
    float* __restrict__ ce_neg,
    const int* __restrict__ np_part, const float* __restrict__ loc_part,
    const float* __restrict__ cep_part,
    const unsigned long long* __restrict__ argm,
    int* __restrict__ done,
    int* __restrict__ np_img, float* __restrict__ loc_img,
    float* __restrict__ cep_img, float* __restrict__ hn_img,
    float* __restrict__ out)
{
    int b = blockIdx.x;
    int tid = threadIdx.x;
    int lane = tid & 63, wid = tid >> 6;

    __shared__ float4 sbox[NM];
    __shared__ int slab[NM], sobj[NM];
    __shared__ unsigned long long sargm[NM][16];
    __shared__ int sK;
    __shared__ int snp;
    __shared__ float sloc, scep;
    __shared__ int red4[4];
    __shared__ float redf4[4];
    __shared__ float sresult;
    __shared__ int samlast;

    if (tid < NM) {
        sbox[tid] = ((const float4*)b_boxes)[b * NM + tid];
        slab[tid] = b_labels[b * NM + tid];
    }
    {   // (a) argm partial reduce: thread (m=tid&15, grp=tid>>4) covers c = grp, grp+16, grp+32
        int m = tid & 15, grp = tid >> 4;
        unsigned long long x = 0;
        for (int c = grp; c < NCH; c += 16)
            { unsigned long long y = argm[(size_t)(b * NCH + c) * NM + m]; x = (y > x) ? y : x; }
        sargm[m][grp] = x;
    }
    __syncthreads();
    if (tid < NM) {
        unsigned long long x = sargm[tid][0];
#pragma unroll
        for (int g = 1; g < 16; ++g) x = (sargm[tid][g] > x) ? sargm[tid][g] : x;
        sobj[tid] = (int)(~(unsigned)(x & 0xffffffffull));
    }
    __syncthreads();

    // (b) force-match fix-up
    float dloc = 0.0f, dcep = 0.0f;
    int dnp = 0;
    if (tid < NM) {
        int pstar = sobj[tid];
        bool first = true;
        for (int m2 = 0; m2 < tid; ++m2) if (sobj[m2] == pstar) first = false;
        if (first) {
            float4 pr = ((const float4*)priors)[pstar];
            float px1 = pr.x - pr.z * 0.5f, py1 = pr.y - pr.w * 0.5f;
            float px2 = pr.x + pr.z * 0.5f, py2 = pr.y + pr.w * 0.5f;
            float area_b = (px2 - px1) * (py2 - py1);
            float best = -1.0f; int bmi = 0;
#pragma unroll
            for (int m = 0; m < NM; ++m) {
                float4 bx = sbox[m];
                float w = fminf(bx.z, px2) - fmaxf(bx.x, px1); w = fmaxf(w, 0.0f);
                float h = fminf(bx.w, py2) - fmaxf(bx.y, py1); h = fmaxf(h, 0.0f);
                float inter = w * h;
                float area_a = (bx.z - bx.x) * (bx.w - bx.y);
                float iou = inter / (area_a + area_b - inter);
                if (iou > best) { best = iou; bmi = m; }   // same order as K1
            }
            // recompute offsets for just bmi and tid (no scratch arrays)
            float4 bxr = sbox[bmi];
            float gr0 = ((bxr.x + bxr.z) * 0.5f - pr.x) / (pr.z / 10.0f);
            float gr1 = ((bxr.y + bxr.w) * 0.5f - pr.y) / (pr.w / 10.0f);
            float gr2 = logf((bxr.z - bxr.x) / pr.z) * 5.0f;
            float gr3 = logf((bxr.w - bxr.y) / pr.w) * 5.0f;
            float4 bxn = sbox[tid];
            float gn0 = ((bxn.x + bxn.z) * 0.5f - pr.x) / (pr.z / 10.0f);
            float gn1 = ((bxn.y + bxn.w) * 0.5f - pr.y) / (pr.w / 10.0f);
            float gn2 = logf((bxn.z - bxn.x) / pr.z) * 5.0f;
            float gn3 = logf((bxn.w - bxn.y) / pr.w) * 5.0f;

            bool pos_raw = best >= 0.5f;
            int lab_raw = slab[bmi];
            int tc_raw = pos_raw ? lab_raw : ((lab_raw == 0) ? 0 : BG);
            int tc_new = slab[tid];                  // forced match to object `tid`

            const float* lg = pred_cls + (size_t)(b * NP + pstar) * NC;
            float l[NC];
            float mx = -INFINITY;
#pragma unroll
            for (int c = 0; c < NC; ++c) { l[c] = lg[c]; mx = fmaxf(mx, l[c]); }
            float se = 0.0f;
#pragma unroll
            for (int c = 0; c < NC; ++c) se += expf(l[c] - mx);
            float lraw_tc = 0.0f, lnew_tc = 0.0f;
#pragma unroll
            for (int c = 0; c < NC; ++c) {
                lraw_tc = (c == tc_raw) ? l[c] : lraw_tc;
                lnew_tc = (c == tc_new) ? l[c] : lnew_tc;
            }
            float lse = mx + logf(se);
            float ce_raw = lse - lraw_tc;
            float ce_new = lse - lnew_tc;

            float4 plv = ((const float4*)pred_loc)[(size_t)b * NP + pstar];
            float loc_raw = fabsf(plv.x - gr0) + fabsf(plv.y - gr1) +
                            fabsf(plv.z - gr2) + fabsf(plv.w - gr3);
            float loc_new = fabsf(plv.x - gn0) + fabsf(plv.y - gn1) +
                            fabsf(plv.z - gn2) + fabsf(plv.w - gn3);

            dnp  = pos_raw ? 0 : 1;
            dloc = loc_new - (pos_raw ? loc_raw : 0.0f);
            dcep = ce_new - (pos_raw ? ce_raw : 0.0f);
            ce_neg[(size_t)b * NP + pstar] = 0.0f;   // now positive -> excluded
        }
    }

    // wave 0: drain patch stores, reduce per-image sums (35 partials + deltas), publish K
    if (wid == 0) {
        asm volatile("s_waitcnt vmcnt(0)" ::: "memory");
        int   np_s  = ((lane < NCH) ? np_part[b * NCH + lane]  : 0)    + dnp;
        float loc_s = ((lane < NCH) ? loc_part[b * NCH + lane] : 0.0f) + dloc;
        float cep_s = ((lane < NCH) ? cep_part[b * NCH + lane] : 0.0f) + dcep;
#pragma unroll
        for (int o = 32; o > 0; o >>= 1) {
            np_s  += __shfl_xor(np_s, o);
            loc_s += __shfl_xor(loc_s, o);
            cep_s += __shfl_xor(cep_s, o);
        }
        if (lane == 0) {
            snp = np_s; sloc = loc_s; scep = cep_s;
            int K = 3 * np_s; if (K > NP) K = NP;
            sK = K;
        }
    }
    __syncthreads();   // patch visible to all waves; K published
    int K = sK;

    // (c) register-resident radix top-K over 256 threads
    const float* src = ce_neg + (size_t)b * NP;
    unsigned v[VPL];
#pragma unroll
    for (int j = 0; j < VPL; ++j) {
        int i = tid + j * 256;                          // coalesced
        v[j] = (i < NP) ? __float_as_uint(src[i]) : 0u; // pad 0: never counted
    }

    if (K > 0) {                                        // K block-uniform
        unsigned V = 0;
        bool exact = false;
#pragma unroll 1
        for (int bit = 30; bit >= 9; --bit) {
            unsigned cand = V | (1u << bit);
            int c = 0;
#pragma unroll
            for (int j = 0; j < VPL; ++j) c += (v[j] >= cand) ? 1 : 0;  // pure VALU
#pragma unroll
            for (int o = 32; o > 0; o >>= 1) c += __shfl_xor(c, o);
            if (lane == 0) red4[wid] = c;
            __syncthreads();
            int ct = red4[0] + red4[1] + red4[2] + red4[3];
            __syncthreads();
            if (ct >= K) {
                V = cand;
                if (ct == K) { exact = true; break; }   // {u >= V} is exactly top-K
            }
        }

        float sum = 0.0f;
        int cgt = 0;
        if (exact) {
#pragma unroll
            for (int j = 0; j < VPL; ++j)
                sum += (v[j] >= V) ? __uint_as_float(v[j]) : 0.0f;
        } else {
#pragma unroll
            for (int j = 0; j < VPL; ++j) {
                bool g = v[j] > V;
                cgt += g ? 1 : 0;
                sum += g ? __uint_as_float(v[j]) : 0.0f;
            }
        }
#pragma unroll
        for (int o = 32; o > 0; o >>= 1) {
            sum += __shfl_xor(sum, o);
            cgt += __shfl_xor(cgt, o);
        }
        if (lane == 0) { red4[wid] = cgt; redf4[wid] = sum; }
        __syncthreads();
        if (tid == 0) {
            float st = redf4[0] + redf4[1] + redf4[2] + redf4[3];
            int   cg = red4[0] + red4[1] + red4[2] + red4[3];
            sresult = exact ? st : st + (float)(K - cg) * __uint_as_float(V);
        }
    } else {
        if (tid == 0) sresult = 0.0f;
    }
    __syncthreads();

    if (tid == 0) {
        np_img[b] = snp; loc_img[b] = sloc; cep_img[b] = scep; hn_img[b] = sresult;
    }

    // (d) last-block ticket finalize
    __threadfence();
    if (tid == 0) samlast = (atomicAdd(done, 1) == NB - 1) ? 1 : 0;
    __syncthreads();
    if (samlast && wid == 0) {
        __threadfence();
        float l2 = loc_img[lane], c2 = cep_img[lane], h2 = hn_img[lane];
        int n2 = np_img[lane];
#pragma unroll
        for (int o = 32; o > 0; o >>= 1) {
            l2 += __shfl_xor(l2, o);
            c2 += __shfl_xor(c2, o);
            h2 += __shfl_xor(h2, o);
            n2 += __shfl_xor(n2, o);
        }
        if (lane == 0) {
            float npt = (float)n2;
            float loc_loss = l2 / (npt * 4.0f);     // ALPHA = 1.0
            float conf_loss = (h2 + c2) / npt;
            out[0] = conf_loss + loc_loss;
            out[1] = loc_loss;
            out[2] = conf_loss;
        }
    }
}

extern "C" void kernel_launch(void* const* d_in, const int* in_sizes, int n_in,
                              void* d_out, int out_size, void* d_ws, size_t ws_size,
                              hipStream_t stream) {
    const float* pred_loc  = (const float*)d_in[0];
    const float* pred_cls  = (const float*)d_in[1];
    const float* b_boxes   = (const float*)d_in[2];
    const int*   b_labels  = (const int*)d_in[3];
    const float* priors    = (const float*)d_in[4];

    char* ws = (char*)d_ws;
    int*   np_part  = (int*)(ws);
    float* loc_part = (float*)(ws + 9216);
    float* cep_part = (float*)(ws + 18432);
    unsigned long long* argm = (unsigned long long*)(ws + 28672);
    int*   done     = (int*)(ws + 315392);
    int*   np_img   = (int*)(ws + 315648);
    float* loc_img  = (float*)(ws + 315904);
    float* cep_img  = (float*)(ws + 316160);
    float* hn_img   = (float*)(ws + 316416);
    float* ce_neg   = (float*)(ws + 320512);
    float* out = (float*)d_out;

    match_kernel<<<NB * NCH, 256, 0, stream>>>(pred_loc, pred_cls, b_boxes,
                                               b_labels, priors, ce_neg, np_part,
                                               loc_part, cep_part, argm, done);
    select_kernel<<<NB, 256, 0, stream>>>(pred_loc, pred_cls, b_boxes, b_labels,
                                          priors, ce_neg, np_part, loc_part,
                                          cep_part, argm, done, np_img, loc_img,
                                          cep_img, hn_img, out);
}